// Round 7
// baseline (34.362 us; speedup 1.0000x reference)
//
#include <hip/hip_runtime.h>

typedef __attribute__((ext_vector_type(8))) short bf16x8;
typedef __attribute__((ext_vector_type(4))) float f32x4;
typedef __attribute__((ext_vector_type(4))) ushort u16x4;

#define C_DIM 256
#define S_DIM 512
#define P_DIM 128
#define K_DIM 512
#define INV_BW 20.0f
#define EPS_LOSS 1e-5f

// ws layout (float offsets) — every cell overwritten each call
#define OFF_SS2    0          // [2][512] fp32 sumsq t2
#define OFF_SS1    1024       // [2][512] fp32 sumsq t1
#define OFF_DIAG   2048       // [2][512] fp32 diag of E
#define OFF_CNTBF  3072       // ushort[128 p][512 s] = 65536 u16 = 32768 float slots
#define OFF_T2BF   35840      // ushort[2][512 s][256 c] = 131072 float slots
#define OFF_T1BF   166912     // ushort[2][512 s][256 c] = 131072 float slots
#define OFF_D1     297984     // float[128 p][2 b][512 t]
#define OFF_D2     429056     // float[128 p][2 b][512 s]
#define OFF_PART   560128     // [128]
#define OFF_TICKET 560256     // [1] int

__device__ inline ushort f2bf(float f) {   // RNE float->bf16 (finite inputs)
  union { float f; uint u; } v; v.f = f;
  return (ushort)((v.u + 0x7FFF + ((v.u >> 16) & 1)) >> 16);
}

// K1: blocks 0..127  -> bf16 transpose + sumsq; one (tensor,b,16-row stripe) each
//     blocks 128..255 -> per-patch histogram -> bf16 cnt[p][s]; re-arms ticket
#define TP 260
__global__ __launch_bounds__(256) void pre_kernel(
    const float* __restrict__ t2, const float* __restrict__ t1,
    const int* __restrict__ idx,
    float* __restrict__ ss2, float* __restrict__ ss1,
    ushort* __restrict__ t2bfT, ushort* __restrict__ t1bfT,
    ushort* __restrict__ cntbf, int* __restrict__ ticket) {
  int blk = blockIdx.x, tid = threadIdx.x;
  if (blk < 128) {
    __shared__ ushort tl[16][TP];
    __shared__ float ps[16][17];
    int tt = blk >> 6, b = (blk >> 5) & 1, stile = blk & 31;
    int s0 = stile * 16;
    const float* src = (tt ? t1 : t2) + b * (C_DIM * S_DIM);
    ushort* dst = (tt ? t1bfT : t2bfT) + b * (S_DIM * C_DIM);
    float* ssd = (tt ? ss1 : ss2) + b * S_DIM;
    int ls = tid & 15, cg = tid >> 4;
    float a = 0.f;
    #pragma unroll
    for (int k = 0; k < 16; ++k) {
      int c = cg + 16 * k;
      float v = src[c * S_DIM + s0 + ls];
      a += v * v;
      tl[ls][c] = f2bf(v);
    }
    ps[cg][ls] = a;
    __syncthreads();
    if (tid < 16) {
      float ss = 0.f;
      #pragma unroll
      for (int j = 0; j < 16; ++j) ss += ps[j][tid];
      ssd[s0 + tid] = ss;
    }
    int wv = tid >> 6, ln = tid & 63;
    #pragma unroll
    for (int i = 0; i < 4; ++i) {
      int sl = wv * 4 + i;
      u16x4 pk = *reinterpret_cast<const u16x4*>(&tl[sl][ln * 4]);
      *reinterpret_cast<u16x4*>(&dst[(s0 + sl) * C_DIM + ln * 4]) = pk;
    }
  } else {
    __shared__ int c_lds[S_DIM];
    int p = blk - 128;
    if (blk == 128 && tid == 0) *ticket = 0;   // re-arm last-arriver each call
    c_lds[tid] = 0; c_lds[tid + 256] = 0;
    __syncthreads();
    atomicAdd(&c_lds[idx[p * K_DIM + tid]], 1);
    atomicAdd(&c_lds[idx[p * K_DIM + tid + 256]], 1);
    __syncthreads();
    cntbf[p * S_DIM + tid]       = f2bf((float)c_lds[tid]);
    cntbf[p * S_DIM + tid + 256] = f2bf((float)c_lds[tid + 256]);
  }
}

// K2: fused Gram+exp+denominator. Block owns a 16-wide FIXED strip:
//  side=0: fixed = t-cols  -> strip E[:,f]  -> D1[p,f] = sum_s cnt[p,s]E[s,f]
//  side=1: fixed = s-rows  -> strip E[f,:]  -> D2[p,f] = sum_t cnt[p,t]E[f,t]
// Stage1: 32 MFMA-tiles (K=256) A=varMat rows, B=fixMat strip (preloaded);
//   epilogue scale+exp -> bf16 -> LDS [fixed16][varying512] (B-frag-ready).
// Stage2: per wave one 16-p tile, K=512 (16 MFMA) A=cnt, B from LDS.
// E never touches global; diag written by side 0.
__global__ __launch_bounds__(512) void gram_denom_kernel(
    const ushort* __restrict__ t2bfT, const ushort* __restrict__ t1bfT,
    const float* __restrict__ ss2, const float* __restrict__ ss1,
    const ushort* __restrict__ cntbf,
    float* __restrict__ D1, float* __restrict__ D2, float* __restrict__ diag) {
  __shared__ ushort ldsE[16][520];          // pitch 520: 16B-aligned rows
  int blk = blockIdx.x;                     // 0..127
  int side = blk >> 6, b = (blk >> 5) & 1, fb = blk & 31;
  int f0 = fb * 16;
  int wave = threadIdx.x >> 6, lane = threadIdx.x & 63;
  int lr = lane & 15, lo = lane >> 4;
  const ushort* varMat = (side ? t1bfT : t2bfT) + b * (S_DIM * C_DIM);
  const ushort* fixMat = (side ? t2bfT : t1bfT) + b * (S_DIM * C_DIM);
  const float* vss = (side ? ss1 : ss2) + b * S_DIM;
  const float* fss = (side ? ss2 : ss1) + b * S_DIM;
  float fscale = 1.0f / fmaxf(sqrtf(fss[f0 + lr]), 1e-12f);
  bf16x8 ffr[8];                            // fixed-strip B fragments, K=256
  #pragma unroll
  for (int k = 0; k < 8; ++k)
    ffr[k] = *reinterpret_cast<const bf16x8*>(
        fixMat + (f0 + lr) * C_DIM + lo * 8 + k * 32);
  #pragma unroll
  for (int i = 0; i < 4; ++i) {             // 4 varying-tiles per wave
    int v0 = (wave * 4 + i) * 16;
    const ushort* ap = varMat + (v0 + lr) * C_DIM + lo * 8;
    f32x4 acc = {0.f, 0.f, 0.f, 0.f};
    #pragma unroll
    for (int k = 0; k < 8; ++k) {
      bf16x8 af = *reinterpret_cast<const bf16x8*>(ap + k * 32);
      acc = __builtin_amdgcn_mfma_f32_16x16x32_bf16(af, ffr[k], acc, 0, 0, 0);
    }
    ushort eb[4];
    #pragma unroll
    for (int r = 0; r < 4; ++r) {
      int vrow = v0 + lo * 4 + r;
      float vs = 1.0f / fmaxf(sqrtf(vss[vrow]), 1e-12f);
      float e = expf(acc[r] * vs * fscale * INV_BW);
      eb[r] = f2bf(e);
      if (side == 0 && vrow == f0 + lr) diag[b * S_DIM + vrow] = e;
    }
    u16x4 pk = {eb[0], eb[1], eb[2], eb[3]};
    *reinterpret_cast<u16x4*>(&ldsE[lr][v0 + lo * 4]) = pk;   // [fix][var]
  }
  __syncthreads();
  int p0 = wave * 16;                       // stage 2: one p-tile per wave
  const ushort* cp = cntbf + (p0 + lr) * S_DIM + lo * 8;
  f32x4 acc = {0.f, 0.f, 0.f, 0.f};
  #pragma unroll
  for (int k = 0; k < 16; ++k) {
    bf16x8 af = *reinterpret_cast<const bf16x8*>(cp + k * 32);
    bf16x8 bf_ = *reinterpret_cast<const bf16x8*>(&ldsE[lr][lo * 8 + k * 32]);
    acc = __builtin_amdgcn_mfma_f32_16x16x32_bf16(af, bf_, acc, 0, 0, 0);
  }
  float* Dout = side ? D2 : D1;
  #pragma unroll
  for (int r = 0; r < 4; ++r) {
    int p = p0 + lo * 4 + r;
    Dout[(p * 2 + b) * S_DIM + f0 + lr] = acc[r];
  }
}

// K3: loss terms + last-arriver final reduction.
__global__ __launch_bounds__(512) void loss_final_kernel(
    const int* __restrict__ idx, const float* __restrict__ diag,
    const float* __restrict__ D1, const float* __restrict__ D2,
    float* __restrict__ part, int* __restrict__ ticket, float* __restrict__ out) {
  int p = blockIdx.x, k = threadIdx.x;
  int s = idx[p * K_DIM + k];
  float acc = 0.f;
  #pragma unroll
  for (int b = 0; b < 2; ++b) {
    float pos = diag[b * S_DIM + s];
    int o = (p * 2 + b) * S_DIM + s;
    float d1 = D1[o];
    float d2 = D2[o];
    acc += logf(0.5f * (pos / d1 + pos / d2) + EPS_LOSS);
  }
  for (int o = 32; o; o >>= 1) acc += __shfl_down(acc, o);
  __shared__ float red[8];
  __shared__ int lastflag;
  if ((k & 63) == 0) red[k >> 6] = acc;
  __syncthreads();
  if (k == 0) {
    float tsum = 0.f;
    #pragma unroll
    for (int i = 0; i < 8; ++i) tsum += red[i];
    atomicExch(&part[p], tsum);
    __threadfence();
    int old = atomicAdd(ticket, 1);
    lastflag = (old == P_DIM - 1);
  }
  __syncthreads();
  if (lastflag) {
    __threadfence();
    float v = (k < P_DIM) ? atomicAdd(&part[k], 0.0f) : 0.0f;
    for (int o = 32; o; o >>= 1) v += __shfl_down(v, o);
    __shared__ float red2[8];
    if ((k & 63) == 0) red2[k >> 6] = v;
    __syncthreads();
    if (k == 0) {
      float tsum = 0.f;
      #pragma unroll
      for (int i = 0; i < 8; ++i) tsum += red2[i];
      out[0] = -tsum * (1.0f / (P_DIM * 2.0f * K_DIM));
    }
  }
}

extern "C" void kernel_launch(void* const* d_in, const int* in_sizes, int n_in,
                              void* d_out, int out_size, void* d_ws, size_t ws_size,
                              hipStream_t stream) {
  const float* t2 = (const float*)d_in[0];
  const float* t1 = (const float*)d_in[1];
  const int* idx  = (const int*)d_in[2];
  float* ws = (float*)d_ws;
  float*  ss2    = ws + OFF_SS2;
  float*  ss1    = ws + OFF_SS1;
  float*  diag   = ws + OFF_DIAG;
  ushort* cntbf  = (ushort*)(ws + OFF_CNTBF);
  ushort* t2bfT  = (ushort*)(ws + OFF_T2BF);
  ushort* t1bfT  = (ushort*)(ws + OFF_T1BF);
  float*  D1     = ws + OFF_D1;
  float*  D2     = ws + OFF_D2;
  float*  part   = ws + OFF_PART;
  int*    ticket = (int*)(ws + OFF_TICKET);

  pre_kernel<<<256, 256, 0, stream>>>(t2, t1, idx, ss2, ss1, t2bfT, t1bfT,
                                      cntbf, ticket);
  gram_denom_kernel<<<128, 512, 0, stream>>>(t2bfT, t1bfT, ss2, ss1, cntbf,
                                             D1, D2, diag);
  loss_final_kernel<<<P_DIM, 512, 0, stream>>>(idx, diag, D1, D2, part, ticket,
                                               (float*)d_out);
}